// Round 1
// baseline (10465.690 us; speedup 1.0000x reference)
//
#include <hip/hip_runtime.h>

#define E_TOTAL 40000
#define TILE 8
#define K1 2432          // 19*128 rows of conv1 input
#define H1 1472          // 19*64 + 256 gate scalars
#define O1P 9            // padded stride for conv2 output (bank-conflict-free col reads)

__device__ __forceinline__ float sigm(float v) { return 1.0f / (1.0f + __expf(-v)); }

__device__ __forceinline__ float wave_sum64(float v) {
#pragma unroll
  for (int off = 32; off >= 1; off >>= 1) v += __shfl_xor(v, off, 64);
  return v;
}

__global__ __launch_bounds__(256, 1)
void edgewise_fused(const float* __restrict__ x, const float* __restrict__ x_edge,
                    const float* __restrict__ edge_dist, const int* __restrict__ edge_index,
                    const float* __restrict__ wig, const float* __restrict__ winv,
                    const float* __restrict__ rw0, const float* __restrict__ rb0,
                    const float* __restrict__ rg0, const float* __restrict__ rbe0,
                    const float* __restrict__ rw1, const float* __restrict__ rb1,
                    const float* __restrict__ rg1, const float* __restrict__ rbe1,
                    const float* __restrict__ rw2, const float* __restrict__ rb2,
                    const float* __restrict__ c1w, const float* __restrict__ c1b,
                    const float* __restrict__ m1w, const float* __restrict__ m2w,
                    const float* __restrict__ c2w, const float* __restrict__ c2b,
                    const float* __restrict__ n1w, const float* __restrict__ n2w,
                    float* __restrict__ out)
{
  __shared__ float s_x[K1 * TILE];   // 77824 B: conv1 input (scaled), later conv2 out (stride 9)
  __shared__ float s_h[H1 * TILE];   // 47104 B: wigner staging / radial temps / conv1 out+gates

  const int t  = threadIdx.x;
  const int e0 = blockIdx.x * TILE;

  // ================= Stage A: gather + wigner einsum -> s_x (unscaled) =================
  for (int i = t; i < 475 * TILE; i += 256) s_h[i] = wig[(size_t)e0 * 475 + i];
  __syncthreads();

  {
    const int c   = t & 127;       // 0..127 combined channel (src|dst)
    const int col = c & 63;
    for (int e = 0; e < TILE; ++e) {
      const int eg   = e0 + e;
      const int node = (c < 64) ? edge_index[eg] : edge_index[E_TOTAL + eg];
      const float* xrow = x + (size_t)node * 1600 + col;
      const float* w = &s_h[e * 475];
      if (t < 128) {               // waves 0,1: m rows 0..9
        float acc[10];
#pragma unroll
        for (int i = 0; i < 10; ++i) acc[i] = 0.f;
        for (int f = 0; f < 25; ++f) {
          const float v = xrow[f * 64];
#pragma unroll
          for (int i = 0; i < 10; ++i) acc[i] = fmaf(w[i * 25 + f], v, acc[i]);
        }
#pragma unroll
        for (int i = 0; i < 10; ++i) s_x[(i * 128 + c) * TILE + e] = acc[i];
      } else {                     // waves 2,3: m rows 10..18
        float acc[9];
#pragma unroll
        for (int i = 0; i < 9; ++i) acc[i] = 0.f;
        for (int f = 0; f < 25; ++f) {
          const float v = xrow[f * 64];
#pragma unroll
          for (int i = 0; i < 9; ++i) acc[i] = fmaf(w[(10 + i) * 25 + f], v, acc[i]);
        }
#pragma unroll
        for (int i = 0; i < 9; ++i) s_x[((10 + i) * 128 + c) * TILE + e] = acc[i];
      }
    }
  }
  __syncthreads();

  // ================= Stage B: radial MLP, scale s_x in place =================
  float* s_xe = s_h;          // [8][128] x_edge tile
  float* s_t0 = s_h + 1024;   // [64][8]  h0 (channel-major)
  float* s_t1 = s_h + 1536;   // [64][8]  h1

  for (int i = t; i < TILE * 128; i += 256)
    s_xe[i] = x_edge[(size_t)(e0 + (i >> 7)) * 128 + (i & 127)];
  __syncthreads();

  // B2: h0 = x_edge @ w0 + b0  (pre-LN), transposed store
  for (int o = t; o < 512; o += 256) {
    const int e = o >> 6, j = o & 63;
    float acc = rb0[j];
#pragma unroll 4
    for (int k = 0; k < 128; ++k) acc = fmaf(s_xe[e * 128 + k], rw0[k * 64 + j], acc);
    s_t0[j * TILE + e] = acc;
  }
  __syncthreads();
  { // LN + silu (one wave per edge, 2 edges per wave sequentially)
    const int j = t & 63, w = t >> 6;
#pragma unroll
    for (int ep = 0; ep < 2; ++ep) {
      const int e = w + ep * 4;
      const float v  = s_t0[j * TILE + e];
      const float mu = wave_sum64(v) * (1.f / 64.f);
      const float d  = v - mu;
      const float var = wave_sum64(d * d) * (1.f / 64.f);
      const float hn = d * rsqrtf(var + 1e-5f) * rg0[j] + rbe0[j];
      s_t0[j * TILE + e] = hn * sigm(hn);
    }
  }
  __syncthreads();

  // B3: h1 = h0 @ w1 + b1, LN + silu
  for (int o = t; o < 512; o += 256) {
    const int e = o >> 6, j = o & 63;
    float acc = rb1[j];
#pragma unroll 4
    for (int k = 0; k < 64; ++k) acc = fmaf(s_t0[k * TILE + e], rw1[k * 64 + j], acc);
    s_t1[j * TILE + e] = acc;
  }
  __syncthreads();
  {
    const int j = t & 63, w = t >> 6;
#pragma unroll
    for (int ep = 0; ep < 2; ++ep) {
      const int e = w + ep * 4;
      const float v  = s_t1[j * TILE + e];
      const float mu = wave_sum64(v) * (1.f / 64.f);
      const float d  = v - mu;
      const float var = wave_sum64(d * d) * (1.f / 64.f);
      const float hn = d * rsqrtf(var + 1e-5f) * rg1[j] + rbe1[j];
      s_t1[j * TILE + e] = hn * sigm(hn);
    }
  }
  __syncthreads();

  // B4: rad[r] = h1 @ w2 + b2, multiply into s_x (real+imag slices share rad)
  for (int r = t; r < 1536; r += 256) {
    float acc[TILE];
    const float bias = rb2[r];
#pragma unroll
    for (int e = 0; e < TILE; ++e) acc[e] = bias;
#pragma unroll 4
    for (int k = 0; k < 64; ++k) {
      const float wv = rw2[k * 1536 + r];
      float xv[8];
      *reinterpret_cast<float4*>(&xv[0]) = *reinterpret_cast<const float4*>(&s_t1[k * TILE]);
      *reinterpret_cast<float4*>(&xv[4]) = *reinterpret_cast<const float4*>(&s_t1[k * TILE + 4]);
#pragma unroll
      for (int e = 0; e < TILE; ++e) acc[e] = fmaf(xv[e], wv, acc[e]);
    }
    int i1, i2;
    if (r < 640)       { i1 = r;       i2 = -1;      }
    else if (r < 1152) { i1 = r;       i2 = r + 512; }  // m=1 real/imag
    else               { i1 = r + 512; i2 = r + 896; }  // m=2 real/imag
#pragma unroll
    for (int e = 0; e < TILE; ++e) s_x[i1 * TILE + e] *= acc[e];
    if (i2 >= 0) {
#pragma unroll
      for (int e = 0; e < TILE; ++e) s_x[i2 * TILE + e] *= acc[e];
    }
  }
  __syncthreads();

  // ================= Stage C: SO(2) conv 1 -> s_h =================
  // fc0: (640 -> 576); cols 0..319 -> msg rows 0..4, cols 320..575 -> gates (hk 1216..1471)
  for (int j = t; j < 576; j += 256) {
    float acc[TILE];
    const float bias = c1b[j];
#pragma unroll
    for (int e = 0; e < TILE; ++e) acc[e] = bias;
#pragma unroll 4
    for (int k = 0; k < 640; ++k) {
      const float wv = c1w[k * 576 + j];
      float xv[8];
      *reinterpret_cast<float4*>(&xv[0]) = *reinterpret_cast<const float4*>(&s_x[k * TILE]);
      *reinterpret_cast<float4*>(&xv[4]) = *reinterpret_cast<const float4*>(&s_x[k * TILE + 4]);
#pragma unroll
      for (int e = 0; e < TILE; ++e) acc[e] = fmaf(xv[e], wv, acc[e]);
    }
    const int hk = (j < 320) ? j : j + 896;
#pragma unroll
    for (int e = 0; e < TILE; ++e) s_h[hk * TILE + e] = acc[e];
  }

  // m=1: (2x512 -> 2x256cols): out_r -> hk 320..575, out_i -> hk 576..831
  {
    const int j = t;  // 0..255
    float ar[TILE], ai[TILE];
#pragma unroll
    for (int e = 0; e < TILE; ++e) { ar[e] = 0.f; ai[e] = 0.f; }
#pragma unroll 2
    for (int k = 0; k < 512; ++k) {
      const float wA = m1w[k * 512 + j];
      const float wB = m1w[k * 512 + 256 + j];
      float xr[8], xi[8];
      *reinterpret_cast<float4*>(&xr[0]) = *reinterpret_cast<const float4*>(&s_x[(640 + k) * TILE]);
      *reinterpret_cast<float4*>(&xr[4]) = *reinterpret_cast<const float4*>(&s_x[(640 + k) * TILE + 4]);
      *reinterpret_cast<float4*>(&xi[0]) = *reinterpret_cast<const float4*>(&s_x[(1152 + k) * TILE]);
      *reinterpret_cast<float4*>(&xi[4]) = *reinterpret_cast<const float4*>(&s_x[(1152 + k) * TILE + 4]);
#pragma unroll
      for (int e = 0; e < TILE; ++e) {
        ar[e] = fmaf(xr[e], wA, fmaf(-xi[e], wB, ar[e]));
        ai[e] = fmaf(xr[e], wB, fmaf( xi[e], wA, ai[e]));
      }
    }
#pragma unroll
    for (int e = 0; e < TILE; ++e) {
      s_h[(320 + j) * TILE + e] = ar[e];
      s_h[(576 + j) * TILE + e] = ai[e];
    }
  }

  // m=2: (2x384 -> 2x192cols): out_r -> hk 832..1023, out_i -> hk 1024..1215
  if (t < 192) {
    const int j = t;
    float ar[TILE], ai[TILE];
#pragma unroll
    for (int e = 0; e < TILE; ++e) { ar[e] = 0.f; ai[e] = 0.f; }
#pragma unroll 2
    for (int k = 0; k < 384; ++k) {
      const float wA = m2w[k * 384 + j];
      const float wB = m2w[k * 384 + 192 + j];
      float xr[8], xi[8];
      *reinterpret_cast<float4*>(&xr[0]) = *reinterpret_cast<const float4*>(&s_x[(1664 + k) * TILE]);
      *reinterpret_cast<float4*>(&xr[4]) = *reinterpret_cast<const float4*>(&s_x[(1664 + k) * TILE + 4]);
      *reinterpret_cast<float4*>(&xi[0]) = *reinterpret_cast<const float4*>(&s_x[(2048 + k) * TILE]);
      *reinterpret_cast<float4*>(&xi[4]) = *reinterpret_cast<const float4*>(&s_x[(2048 + k) * TILE + 4]);
#pragma unroll
      for (int e = 0; e < TILE; ++e) {
        ar[e] = fmaf(xr[e], wA, fmaf(-xi[e], wB, ar[e]));
        ai[e] = fmaf(xr[e], wB, fmaf( xi[e], wA, ai[e]));
      }
    }
#pragma unroll
    for (int e = 0; e < TILE; ++e) {
      s_h[(832 + j) * TILE + e]  = ar[e];
      s_h[(1024 + j) * TILE + e] = ai[e];
    }
  }
  __syncthreads();

  // ================= Stage D: gating =================
  for (int hk = t; hk < 1216; hk += 256) {
    const int m = hk >> 6, cc = hk & 63;
#pragma unroll
    for (int e = 0; e < TILE; ++e) {
      float v = s_h[hk * TILE + e];
      if (m == 0) {
        v = v * sigm(v);
      } else {
        const int gidx = ((m <= 12) ? ((m - 1) & 3) : (1 + (m - 13) % 3)) * 64 + cc;
        v *= sigm(s_h[(1216 + gidx) * TILE + e]);
      }
      s_h[hk * TILE + e] = v;
    }
  }
  __syncthreads();

  // ================= Stage E: SO(2) conv 2 -> s_o (alias s_x, stride 9) =================
  float* s_o = s_x;
  for (int j = t; j < 320; j += 256) {
    float acc[TILE];
    const float bias = c2b[j];
#pragma unroll
    for (int e = 0; e < TILE; ++e) acc[e] = bias;
#pragma unroll 4
    for (int k = 0; k < 320; ++k) {
      const float wv = c2w[k * 320 + j];
      float xv[8];
      *reinterpret_cast<float4*>(&xv[0]) = *reinterpret_cast<const float4*>(&s_h[k * TILE]);
      *reinterpret_cast<float4*>(&xv[4]) = *reinterpret_cast<const float4*>(&s_h[k * TILE + 4]);
#pragma unroll
      for (int e = 0; e < TILE; ++e) acc[e] = fmaf(xv[e], wv, acc[e]);
    }
#pragma unroll
    for (int e = 0; e < TILE; ++e) s_o[j * O1P + e] = acc[e];
  }
  {
    const int j = t;  // 0..255
    float ar[TILE], ai[TILE];
#pragma unroll
    for (int e = 0; e < TILE; ++e) { ar[e] = 0.f; ai[e] = 0.f; }
#pragma unroll 2
    for (int k = 0; k < 256; ++k) {
      const float wA = n1w[k * 512 + j];
      const float wB = n1w[k * 512 + 256 + j];
      float xr[8], xi[8];
      *reinterpret_cast<float4*>(&xr[0]) = *reinterpret_cast<const float4*>(&s_h[(320 + k) * TILE]);
      *reinterpret_cast<float4*>(&xr[4]) = *reinterpret_cast<const float4*>(&s_h[(320 + k) * TILE + 4]);
      *reinterpret_cast<float4*>(&xi[0]) = *reinterpret_cast<const float4*>(&s_h[(576 + k) * TILE]);
      *reinterpret_cast<float4*>(&xi[4]) = *reinterpret_cast<const float4*>(&s_h[(576 + k) * TILE + 4]);
#pragma unroll
      for (int e = 0; e < TILE; ++e) {
        ar[e] = fmaf(xr[e], wA, fmaf(-xi[e], wB, ar[e]));
        ai[e] = fmaf(xr[e], wB, fmaf( xi[e], wA, ai[e]));
      }
    }
#pragma unroll
    for (int e = 0; e < TILE; ++e) {
      s_o[(320 + j) * O1P + e] = ar[e];
      s_o[(576 + j) * O1P + e] = ai[e];
    }
  }
  if (t < 192) {
    const int j = t;
    float ar[TILE], ai[TILE];
#pragma unroll
    for (int e = 0; e < TILE; ++e) { ar[e] = 0.f; ai[e] = 0.f; }
#pragma unroll 2
    for (int k = 0; k < 192; ++k) {
      const float wA = n2w[k * 384 + j];
      const float wB = n2w[k * 384 + 192 + j];
      float xr[8], xi[8];
      *reinterpret_cast<float4*>(&xr[0]) = *reinterpret_cast<const float4*>(&s_h[(832 + k) * TILE]);
      *reinterpret_cast<float4*>(&xr[4]) = *reinterpret_cast<const float4*>(&s_h[(832 + k) * TILE + 4]);
      *reinterpret_cast<float4*>(&xi[0]) = *reinterpret_cast<const float4*>(&s_h[(1024 + k) * TILE]);
      *reinterpret_cast<float4*>(&xi[4]) = *reinterpret_cast<const float4*>(&s_h[(1024 + k) * TILE + 4]);
#pragma unroll
      for (int e = 0; e < TILE; ++e) {
        ar[e] = fmaf(xr[e], wA, fmaf(-xi[e], wB, ar[e]));
        ai[e] = fmaf(xr[e], wB, fmaf( xi[e], wA, ai[e]));
      }
    }
#pragma unroll
    for (int e = 0; e < TILE; ++e) {
      s_o[(832 + j) * O1P + e]  = ar[e];
      s_o[(1024 + j) * O1P + e] = ai[e];
    }
  }
  __syncthreads();

  // ================= Stage F: envelope * (wigner_inv @ msg), scatter-add =================
  for (int i = t; i < 475 * TILE; i += 256) s_h[i] = winv[(size_t)e0 * 475 + i];
  __syncthreads();

  {
    const int cc = t & 63;
    const int fg = t >> 6;
    for (int e = 0; e < TILE; ++e) {
      const int eg = e0 + e;
      const float dd = edge_dist[eg] * (1.f / 6.f);
      float env = 0.f;
      if (dd < 1.f) {
        const float d5 = dd * dd * dd * dd * dd;
        env = 1.f - 21.f * d5 + 35.f * d5 * dd - 15.f * d5 * dd * dd;
      }
      const int dst = edge_index[E_TOTAL + eg];
      float* obase = out + (size_t)dst * 1600 + cc;
      const float* wv = &s_h[e * 475];
      for (int f = fg; f < 25; f += 4) {
        float acc = 0.f;
#pragma unroll
        for (int m = 0; m < 19; ++m)
          acc = fmaf(wv[f * 19 + m], s_o[(m * 64 + cc) * O1P + e], acc);
        atomicAdd(obase + f * 64, acc * env);
      }
    }
  }
}

extern "C" void kernel_launch(void* const* d_in, const int* in_sizes, int n_in,
                              void* d_out, int out_size, void* d_ws, size_t ws_size,
                              hipStream_t stream) {
  (void)in_sizes; (void)n_in; (void)d_ws; (void)ws_size;
  const float* x    = (const float*)d_in[0];
  const float* xe   = (const float*)d_in[1];
  const float* ed   = (const float*)d_in[2];
  const int*   eidx = (const int*)  d_in[3];
  const float* wg   = (const float*)d_in[4];
  const float* wi   = (const float*)d_in[5];
  const float* rw0  = (const float*)d_in[6];
  const float* rb0  = (const float*)d_in[7];
  const float* rg0  = (const float*)d_in[8];
  const float* rbe0 = (const float*)d_in[9];
  const float* rw1  = (const float*)d_in[10];
  const float* rb1  = (const float*)d_in[11];
  const float* rg1  = (const float*)d_in[12];
  const float* rbe1 = (const float*)d_in[13];
  const float* rw2  = (const float*)d_in[14];
  const float* rb2  = (const float*)d_in[15];
  const float* c1w  = (const float*)d_in[16];
  const float* c1b  = (const float*)d_in[17];
  const float* m1w  = (const float*)d_in[18];
  const float* m2w  = (const float*)d_in[19];
  const float* c2w  = (const float*)d_in[20];
  const float* c2b  = (const float*)d_in[21];
  const float* n1w  = (const float*)d_in[22];
  const float* n2w  = (const float*)d_in[23];
  float* out = (float*)d_out;

  hipMemsetAsync(d_out, 0, (size_t)out_size * sizeof(float), stream);
  hipLaunchKernelGGL(edgewise_fused, dim3(E_TOTAL / TILE), dim3(256), 0, stream,
                     x, xe, ed, eidx, wg, wi,
                     rw0, rb0, rg0, rbe0, rw1, rb1, rg1, rbe1, rw2, rb2,
                     c1w, c1b, m1w, m2w, c2w, c2b, n1w, n2w, out);
}

// Round 3
// 1359.802 us; speedup vs baseline: 7.6965x; 7.6965x over previous
//
#include <hip/hip_runtime.h>

#define NE 40000

typedef unsigned short u16;
typedef __attribute__((ext_vector_type(8))) unsigned short ushort8;
typedef __attribute__((ext_vector_type(4))) short short4v;
typedef __attribute__((ext_vector_type(4))) float float4v;

__device__ __forceinline__ u16 f2b(float f) {
  union { float f; unsigned u; } v; v.f = f;
  unsigned r = v.u + 0x7FFFu + ((v.u >> 16) & 1u);
  return (u16)(r >> 16);
}
__device__ __forceinline__ float b2f(u16 h) {
  union { unsigned u; float f; } v; v.u = ((unsigned)h) << 16;
  return v.f;
}
__device__ __forceinline__ float sigm(float v) { return 1.0f / (1.0f + __expf(-v)); }
__device__ __forceinline__ float wave_sum64(float v) {
#pragma unroll
  for (int off = 32; off >= 1; off >>= 1) v += __shfl_xor(v, off, 64);
  return v;
}

// ---------------- weight packing: [K][N] f32 -> bf16 packed[(k/4)][n][k%4] ----------------
__global__ void pack_plain(const float* __restrict__ src, u16* __restrict__ dst, int N) {
  const int k = blockIdx.x;
  for (int n = threadIdx.x; n < N; n += 256)
    dst[(size_t)(k >> 2) * (N * 4) + n * 4 + (k & 3)] = f2b(src[(size_t)k * N + n]);
}
// complex stack: out[k][n], K=2*Ks: k<Ks: src[k][n]; else n<half ? -src[k-Ks][n+half] : src[k-Ks][n-half]
__global__ void pack_cplx(const float* __restrict__ src, u16* __restrict__ dst, int Ks, int N, int half) {
  const int k = blockIdx.x;  // 0..2*Ks-1
  for (int n = threadIdx.x; n < N; n += 256) {
    float v;
    if (k < Ks) v = src[(size_t)k * N + n];
    else        v = (n < half) ? -src[(size_t)(k - Ks) * N + n + half]
                               :  src[(size_t)(k - Ks) * N + n - half];
    dst[(size_t)(k >> 2) * (N * 4) + n * 4 + (k & 3)] = f2b(v);
  }
}

// ---------------- radial MLP front (2 layers + LN + silu) -> h1[Ec][64] bf16 ----------------
__global__ __launch_bounds__(256, 2)
void radial_front(const float* __restrict__ xe, int eBase,
                  const float* __restrict__ rw0, const float* __restrict__ rb0,
                  const float* __restrict__ rg0, const float* __restrict__ rbe0,
                  const float* __restrict__ rw1, const float* __restrict__ rb1,
                  const float* __restrict__ rg1, const float* __restrict__ rbe1,
                  u16* __restrict__ h1) {
  __shared__ float s_xe[32 * 132];
  __shared__ float s_a[64 * 34];
  __shared__ float s_b[64 * 34];
  const int t = threadIdx.x;
  const int e0 = blockIdx.x * 32;  // chunk-local
  for (int c = t; c < 1024; c += 256) {
    const int row = c >> 5, q = c & 31;
    *(float4*)&s_xe[row * 132 + q * 4] = *(const float4*)&xe[(size_t)(eBase + e0 + row) * 128 + q * 4];
  }
  __syncthreads();
  for (int o = t; o < 2048; o += 256) {
    const int e = o & 31, j = o >> 5;
    float acc = rb0[j];
#pragma unroll 4
    for (int k = 0; k < 128; ++k) acc = fmaf(s_xe[e * 132 + k], rw0[k * 64 + j], acc);
    s_a[j * 34 + e] = acc;
  }
  __syncthreads();
  {
    const int w = t >> 6, l = t & 63;
#pragma unroll
    for (int ei = 0; ei < 8; ++ei) {
      const int e = w * 8 + ei;
      float v = s_a[l * 34 + e];
      const float mu = wave_sum64(v) * (1.f / 64.f);
      const float dd = v - mu;
      const float var = wave_sum64(dd * dd) * (1.f / 64.f);
      const float hn = dd * rsqrtf(var + 1e-5f) * rg0[l] + rbe0[l];
      s_a[l * 34 + e] = hn * sigm(hn);
    }
  }
  __syncthreads();
  for (int o = t; o < 2048; o += 256) {
    const int e = o & 31, j = o >> 5;
    float acc = rb1[j];
#pragma unroll 4
    for (int k = 0; k < 64; ++k) acc = fmaf(s_a[k * 34 + e], rw1[k * 64 + j], acc);
    s_b[j * 34 + e] = acc;
  }
  __syncthreads();
  {
    const int w = t >> 6, l = t & 63;
#pragma unroll
    for (int ei = 0; ei < 8; ++ei) {
      const int e = w * 8 + ei;
      float v = s_b[l * 34 + e];
      const float mu = wave_sum64(v) * (1.f / 64.f);
      const float dd = v - mu;
      const float var = wave_sum64(dd * dd) * (1.f / 64.f);
      const float hn = dd * rsqrtf(var + 1e-5f) * rg1[l] + rbe1[l];
      h1[(size_t)(e0 + e) * 64 + l] = f2b(hn * sigm(hn));
    }
  }
}

// ---------------- generic bf16 MFMA GEMM: C[M x N] (+bias) = A[M x K] * Bpacked ----------------
// BM=128, BN=64, BK=64; 4 waves, wave tile 32x64 (mt=2, nt=4); 16x16x16 bf16 MFMA.
__global__ __launch_bounds__(256, 2)
void gemm_bf16(const u16* __restrict__ A, int As, int Ao,
               const u16* __restrict__ Bp, const float* __restrict__ bias,
               u16* __restrict__ C, int Cs, int Co, int N, int K, int M) {
  __shared__ u16 sA[128 * 72];
  __shared__ u16 sB[16 * 272];
  const int t = threadIdx.x;
  const int w = t >> 6, l = t & 63, lr = l & 15, g = l >> 4;
  const int m0 = blockIdx.y * 128, n0 = blockIdx.x * 64;
  float4v acc[2][4];
#pragma unroll
  for (int i = 0; i < 2; ++i)
#pragma unroll
    for (int j = 0; j < 4; ++j) acc[i][j] = (float4v){0.f, 0.f, 0.f, 0.f};
  const int N4 = N * 4;
  for (int k0 = 0; k0 < K; k0 += 64) {
#pragma unroll
    for (int i = 0; i < 4; ++i) {  // stage A: 128 rows x 64 k
      const int c = t + i * 256;
      const int row = c >> 3, c8 = c & 7;
      ushort8 v = {0, 0, 0, 0, 0, 0, 0, 0};
      if (m0 + row < M)
        v = *(const ushort8*)&A[(size_t)(m0 + row) * As + Ao + k0 + c8 * 8];
      *(ushort8*)&sA[row * 72 + c8 * 8] = v;
    }
#pragma unroll
    for (int i = 0; i < 2; ++i) {  // stage B: 16 packed rows x 256
      const int c = t + i * 256;
      const int pr = c >> 5, ii = c & 31;
      const ushort8 v = *(const ushort8*)&Bp[(size_t)((k0 >> 2) + pr) * N4 + n0 * 4 + ii * 8];
      *(ushort8*)&sB[pr * 272 + ii * 8] = v;
    }
    __syncthreads();
#pragma unroll
    for (int kk = 0; kk < 4; ++kk) {
      const short4v av0 = *(const short4v*)&sA[(32 * w + lr) * 72 + kk * 16 + 4 * g];
      const short4v av1 = *(const short4v*)&sA[(32 * w + 16 + lr) * 72 + kk * 16 + 4 * g];
#pragma unroll
      for (int nt = 0; nt < 4; ++nt) {
        const short4v bv = *(const short4v*)&sB[(kk * 4 + g) * 272 + (nt * 16 + lr) * 4];
        acc[0][nt] = __builtin_amdgcn_mfma_f32_16x16x16bf16_1k(av0, bv, acc[0][nt], 0, 0, 0);
        acc[1][nt] = __builtin_amdgcn_mfma_f32_16x16x16bf16_1k(av1, bv, acc[1][nt], 0, 0, 0);
      }
    }
    __syncthreads();
  }
#pragma unroll
  for (int mt = 0; mt < 2; ++mt)
#pragma unroll
    for (int nt = 0; nt < 4; ++nt) {
      const int col = n0 + nt * 16 + lr;
      const float bb = bias ? bias[col] : 0.f;
#pragma unroll
      for (int r = 0; r < 4; ++r) {
        const int row = m0 + 32 * w + mt * 16 + 4 * g + r;
        if (row < M) C[(size_t)row * Cs + Co + col] = f2b(acc[mt][nt][r] + bb);
      }
    }
}

// ---------------- gather + wigner einsum + rad scaling -> msg[Ec][2432] bf16 ----------------
__global__ __launch_bounds__(256, 2)
void wigner_fwd(const float* __restrict__ x, const int* __restrict__ eidx,
                const float* __restrict__ wig, const u16* __restrict__ rad,
                u16* __restrict__ msg, int eBase) {
  __shared__ float s_w[1900];
  const int t = threadIdx.x;
  const int el0 = blockIdx.x * 4;
  for (int i = t; i < 1900; i += 256) s_w[i] = wig[(size_t)(eBase + el0) * 475 + i];
  __syncthreads();
  const int w = t >> 6, l = t & 63;
  const int el = el0 + w, eg = eBase + el;
  const int src = eidx[eg], dst = eidx[NE + eg];
  float xs[25], xd[25];
#pragma unroll
  for (int f = 0; f < 25; ++f) {
    xs[f] = x[(size_t)src * 1600 + f * 64 + l];
    xd[f] = x[(size_t)dst * 1600 + f * 64 + l];
  }
  const float* W = s_w + w * 475;
  const u16* rr = rad + (size_t)el * 1536;
  u16* mo = msg + (size_t)el * 2432;
  for (int m = 0; m < 19; ++m) {
    float as = 0.f, ad = 0.f;
#pragma unroll
    for (int f = 0; f < 25; ++f) {
      const float wv = W[m * 25 + f];
      as = fmaf(wv, xs[f], as);
      ad = fmaf(wv, xd[f], ad);
    }
    const int rrow = (m <= 8) ? m : ((m <= 15) ? m - 4 : m - 7);
    mo[m * 128 + l]      = f2b(as * b2f(rr[rrow * 128 + l]));
    mo[m * 128 + 64 + l] = f2b(ad * b2f(rr[rrow * 128 + 64 + l]));
  }
}

// ---------------- gating: h[Ec][1472] -> rows 0..18 in place (cols 0..1215) ----------------
__global__ __launch_bounds__(256, 4)
void gate_kernel(u16* __restrict__ h, int Ec) {
  const int idx = blockIdx.x * 256 + threadIdx.x;
  if (idx >= Ec * 64) return;
  const int e = idx >> 6, c = idx & 63;
  u16* hr = h + (size_t)e * 1472;
  float gg[4];
#pragma unroll
  for (int gi = 0; gi < 4; ++gi) gg[gi] = sigm(b2f(hr[320 + gi * 64 + c]));
  float v[19];
  { const float a = b2f(hr[c]); v[0] = a * sigm(a); }
#pragma unroll
  for (int m = 1; m <= 4; ++m)  v[m] = b2f(hr[m * 64 + c]) * gg[m - 1];
#pragma unroll
  for (int m = 5; m <= 8; ++m)  v[m] = b2f(hr[576 + (m - 5) * 64 + c]) * gg[m - 5];
#pragma unroll
  for (int m = 9; m <= 12; ++m) v[m] = b2f(hr[832 + (m - 9) * 64 + c]) * gg[m - 9];
#pragma unroll
  for (int m = 13; m <= 15; ++m) v[m] = b2f(hr[1088 + (m - 13) * 64 + c]) * gg[m - 12];
#pragma unroll
  for (int m = 16; m <= 18; ++m) v[m] = b2f(hr[1280 + (m - 16) * 64 + c]) * gg[m - 15];
#pragma unroll
  for (int m = 0; m < 19; ++m) hr[m * 64 + c] = f2b(v[m]);
}

// ---------------- envelope * (wigner_inv @ msg3), scatter-add ----------------
__global__ __launch_bounds__(256, 2)
void scatter_kernel(const u16* __restrict__ msg3, const int* __restrict__ eidx,
                    const float* __restrict__ ed, const float* __restrict__ winv,
                    float* __restrict__ out, int eBase) {
  __shared__ float s_w[1900];
  const int t = threadIdx.x;
  const int el0 = blockIdx.x * 4;
  for (int i = t; i < 1900; i += 256) s_w[i] = winv[(size_t)(eBase + el0) * 475 + i];
  __syncthreads();
  const int w = t >> 6, l = t & 63;
  const int el = el0 + w, eg = eBase + el;
  const int dst = eidx[NE + eg];
  const float d = ed[eg] * (1.f / 6.f);
  float env = 0.f;
  if (d < 1.f) {
    const float d5 = d * d * d * d * d;
    env = 1.f - 21.f * d5 + 35.f * d5 * d - 15.f * d5 * d * d;
  }
  float v[19];
#pragma unroll
  for (int m = 0; m < 19; ++m) v[m] = b2f(msg3[(size_t)el * 1216 + m * 64 + l]) * env;
  const float* W = s_w + w * 475;
  float* ob = out + (size_t)dst * 1600 + l;
  for (int f = 0; f < 25; ++f) {
    float a = 0.f;
#pragma unroll
    for (int m = 0; m < 19; ++m) a = fmaf(W[f * 19 + m], v[m], a);
    atomicAdd(ob + f * 64, a);
  }
}

// ==================== fallback: round-1 fused kernel (used only if ws too small) ====================
#define TILE 8
#define K1F 2432
#define H1F 1472
#define O1P 9

__global__ __launch_bounds__(256, 1)
void edgewise_fused(const float* __restrict__ x, const float* __restrict__ x_edge,
                    const float* __restrict__ edge_dist, const int* __restrict__ edge_index,
                    const float* __restrict__ wig, const float* __restrict__ winv,
                    const float* __restrict__ rw0, const float* __restrict__ rb0,
                    const float* __restrict__ rg0, const float* __restrict__ rbe0,
                    const float* __restrict__ rw1, const float* __restrict__ rb1,
                    const float* __restrict__ rg1, const float* __restrict__ rbe1,
                    const float* __restrict__ rw2, const float* __restrict__ rb2,
                    const float* __restrict__ c1w, const float* __restrict__ c1b,
                    const float* __restrict__ m1w, const float* __restrict__ m2w,
                    const float* __restrict__ c2w, const float* __restrict__ c2b,
                    const float* __restrict__ n1w, const float* __restrict__ n2w,
                    float* __restrict__ out)
{
  __shared__ float s_x[K1F * TILE];
  __shared__ float s_h[H1F * TILE];
  const int t  = threadIdx.x;
  const int e0 = blockIdx.x * TILE;
  for (int i = t; i < 475 * TILE; i += 256) s_h[i] = wig[(size_t)e0 * 475 + i];
  __syncthreads();
  {
    const int c   = t & 127;
    const int col = c & 63;
    for (int e = 0; e < TILE; ++e) {
      const int eg   = e0 + e;
      const int node = (c < 64) ? edge_index[eg] : edge_index[NE + eg];
      const float* xrow = x + (size_t)node * 1600 + col;
      const float* w = &s_h[e * 475];
      if (t < 128) {
        float acc[10];
#pragma unroll
        for (int i = 0; i < 10; ++i) acc[i] = 0.f;
        for (int f = 0; f < 25; ++f) {
          const float v = xrow[f * 64];
#pragma unroll
          for (int i = 0; i < 10; ++i) acc[i] = fmaf(w[i * 25 + f], v, acc[i]);
        }
#pragma unroll
        for (int i = 0; i < 10; ++i) s_x[(i * 128 + c) * TILE + e] = acc[i];
      } else {
        float acc[9];
#pragma unroll
        for (int i = 0; i < 9; ++i) acc[i] = 0.f;
        for (int f = 0; f < 25; ++f) {
          const float v = xrow[f * 64];
#pragma unroll
          for (int i = 0; i < 9; ++i) acc[i] = fmaf(w[(10 + i) * 25 + f], v, acc[i]);
        }
#pragma unroll
        for (int i = 0; i < 9; ++i) s_x[((10 + i) * 128 + c) * TILE + e] = acc[i];
      }
    }
  }
  __syncthreads();
  float* s_xe = s_h;
  float* s_t0 = s_h + 1024;
  float* s_t1 = s_h + 1536;
  for (int i = t; i < TILE * 128; i += 256)
    s_xe[i] = x_edge[(size_t)(e0 + (i >> 7)) * 128 + (i & 127)];
  __syncthreads();
  for (int o = t; o < 512; o += 256) {
    const int e = o >> 6, j = o & 63;
    float acc = rb0[j];
#pragma unroll 4
    for (int k = 0; k < 128; ++k) acc = fmaf(s_xe[e * 128 + k], rw0[k * 64 + j], acc);
    s_t0[j * TILE + e] = acc;
  }
  __syncthreads();
  {
    const int j = t & 63, w = t >> 6;
#pragma unroll
    for (int ep = 0; ep < 2; ++ep) {
      const int e = w + ep * 4;
      const float v  = s_t0[j * TILE + e];
      const float mu = wave_sum64(v) * (1.f / 64.f);
      const float d  = v - mu;
      const float var = wave_sum64(d * d) * (1.f / 64.f);
      const float hn = d * rsqrtf(var + 1e-5f) * rg0[j] + rbe0[j];
      s_t0[j * TILE + e] = hn * sigm(hn);
    }
  }
  __syncthreads();
  for (int o = t; o < 512; o += 256) {
    const int e = o >> 6, j = o & 63;
    float acc = rb1[j];
#pragma unroll 4
    for (int k = 0; k < 64; ++k) acc = fmaf(s_t0[k * TILE + e], rw1[k * 64 + j], acc);
    s_t1[j * TILE + e] = acc;
  }
  __syncthreads();
  {
    const int j = t & 63, w = t >> 6;
#pragma unroll
    for (int ep = 0; ep < 2; ++ep) {
      const int e = w + ep * 4;
      const float v  = s_t1[j * TILE + e];
      const float mu = wave_sum64(v) * (1.f / 64.f);
      const float d  = v - mu;
      const float var = wave_sum64(d * d) * (1.f / 64.f);
      const float hn = d * rsqrtf(var + 1e-5f) * rg1[j] + rbe1[j];
      s_t1[j * TILE + e] = hn * sigm(hn);
    }
  }
  __syncthreads();
  for (int r = t; r < 1536; r += 256) {
    float acc[TILE];
    const float bias = rb2[r];
#pragma unroll
    for (int e = 0; e < TILE; ++e) acc[e] = bias;
#pragma unroll 4
    for (int k = 0; k < 64; ++k) {
      const float wv = rw2[k * 1536 + r];
      float xv[8];
      *reinterpret_cast<float4*>(&xv[0]) = *reinterpret_cast<const float4*>(&s_t1[k * TILE]);
      *reinterpret_cast<float4*>(&xv[4]) = *reinterpret_cast<const float4*>(&s_t1[k * TILE + 4]);
#pragma unroll
      for (int e = 0; e < TILE; ++e) acc[e] = fmaf(xv[e], wv, acc[e]);
    }
    int i1, i2;
    if (r < 640)       { i1 = r;       i2 = -1;      }
    else if (r < 1152) { i1 = r;       i2 = r + 512; }
    else               { i1 = r + 512; i2 = r + 896; }
#pragma unroll
    for (int e = 0; e < TILE; ++e) s_x[i1 * TILE + e] *= acc[e];
    if (i2 >= 0) {
#pragma unroll
      for (int e = 0; e < TILE; ++e) s_x[i2 * TILE + e] *= acc[e];
    }
  }
  __syncthreads();
  for (int j = t; j < 576; j += 256) {
    float acc[TILE];
    const float bias = c1b[j];
#pragma unroll
    for (int e = 0; e < TILE; ++e) acc[e] = bias;
#pragma unroll 4
    for (int k = 0; k < 640; ++k) {
      const float wv = c1w[k * 576 + j];
      float xv[8];
      *reinterpret_cast<float4*>(&xv[0]) = *reinterpret_cast<const float4*>(&s_x[k * TILE]);
      *reinterpret_cast<float4*>(&xv[4]) = *reinterpret_cast<const float4*>(&s_x[k * TILE + 4]);
#pragma unroll
      for (int e = 0; e < TILE; ++e) acc[e] = fmaf(xv[e], wv, acc[e]);
    }
    const int hk = (j < 320) ? j : j + 896;
#pragma unroll
    for (int e = 0; e < TILE; ++e) s_h[hk * TILE + e] = acc[e];
  }
  {
    const int j = t;
    float ar[TILE], ai[TILE];
#pragma unroll
    for (int e = 0; e < TILE; ++e) { ar[e] = 0.f; ai[e] = 0.f; }
#pragma unroll 2
    for (int k = 0; k < 512; ++k) {
      const float wA = m1w[k * 512 + j];
      const float wB = m1w[k * 512 + 256 + j];
      float xr[8], xi[8];
      *reinterpret_cast<float4*>(&xr[0]) = *reinterpret_cast<const float4*>(&s_x[(640 + k) * TILE]);
      *reinterpret_cast<float4*>(&xr[4]) = *reinterpret_cast<const float4*>(&s_x[(640 + k) * TILE + 4]);
      *reinterpret_cast<float4*>(&xi[0]) = *reinterpret_cast<const float4*>(&s_x[(1152 + k) * TILE]);
      *reinterpret_cast<float4*>(&xi[4]) = *reinterpret_cast<const float4*>(&s_x[(1152 + k) * TILE + 4]);
#pragma unroll
      for (int e = 0; e < TILE; ++e) {
        ar[e] = fmaf(xr[e], wA, fmaf(-xi[e], wB, ar[e]));
        ai[e] = fmaf(xr[e], wB, fmaf( xi[e], wA, ai[e]));
      }
    }
#pragma unroll
    for (int e = 0; e < TILE; ++e) {
      s_h[(320 + j) * TILE + e] = ar[e];
      s_h[(576 + j) * TILE + e] = ai[e];
    }
  }
  if (t < 192) {
    const int j = t;
    float ar[TILE], ai[TILE];
#pragma unroll
    for (int e = 0; e < TILE; ++e) { ar[e] = 0.f; ai[e] = 0.f; }
#pragma unroll 2
    for (int k = 0; k < 384; ++k) {
      const float wA = m2w[k * 384 + j];
      const float wB = m2w[k * 384 + 192 + j];
      float xr[8], xi[8];
      *reinterpret_cast<float4*>(&xr[0]) = *reinterpret_cast<const float4*>(&s_x[(1664 + k) * TILE]);
      *reinterpret_cast<float4*>(&xr[4]) = *reinterpret_cast<const float4*>(&s_x[(1664 + k) * TILE + 4]);
      *reinterpret_cast<float4*>(&xi[0]) = *reinterpret_cast<const float4*>(&s_x[(2048 + k) * TILE]);
      *reinterpret_cast<float4*>(&xi[4]) = *reinterpret_cast<const float4*>(&s_x[(2048 + k) * TILE + 4]);
#pragma unroll
      for (int e = 0; e < TILE; ++e) {
        ar[e] = fmaf(xr[e], wA, fmaf(-xi[e], wB, ar[e]));
        ai[e] = fmaf(xr[e], wB, fmaf( xi[e], wA, ai[e]));
      }
    }
#pragma unroll
    for (int e = 0; e < TILE; ++e) {
      s_h[(832 + j) * TILE + e]  = ar[e];
      s_h[(1024 + j) * TILE + e] = ai[e];
    }
  }
  __syncthreads();
  for (int hk = t; hk < 1216; hk += 256) {
    const int m = hk >> 6, cc = hk & 63;
#pragma unroll
    for (int e = 0; e < TILE; ++e) {
      float v = s_h[hk * TILE + e];
      if (m == 0) {
        v = v * sigm(v);
      } else {
        const int gidx = ((m <= 12) ? ((m - 1) & 3) : (1 + (m - 13) % 3)) * 64 + cc;
        v *= sigm(s_h[(1216 + gidx) * TILE + e]);
      }
      s_h[hk * TILE + e] = v;
    }
  }
  __syncthreads();
  float* s_o = s_x;
  for (int j = t; j < 320; j += 256) {
    float acc[TILE];
    const float bias = c2b[j];
#pragma unroll
    for (int e = 0; e < TILE; ++e) acc[e] = bias;
#pragma unroll 4
    for (int k = 0; k < 320; ++k) {
      const float wv = c2w[k * 320 + j];
      float xv[8];
      *reinterpret_cast<float4*>(&xv[0]) = *reinterpret_cast<const float4*>(&s_h[k * TILE]);
      *reinterpret_cast<float4*>(&xv[4]) = *reinterpret_cast<const float4*>(&s_h[k * TILE + 4]);
#pragma unroll
      for (int e = 0; e < TILE; ++e) acc[e] = fmaf(xv[e], wv, acc[e]);
    }
#pragma unroll
    for (int e = 0; e < TILE; ++e) s_o[j * O1P + e] = acc[e];
  }
  {
    const int j = t;
    float ar[TILE], ai[TILE];
#pragma unroll
    for (int e = 0; e < TILE; ++e) { ar[e] = 0.f; ai[e] = 0.f; }
#pragma unroll 2
    for (int k = 0; k < 256; ++k) {
      const float wA = n1w[k * 512 + j];
      const float wB = n1w[k * 512 + 256 + j];
      float xr[8], xi[8];
      *reinterpret_cast<float4*>(&xr[0]) = *reinterpret_cast<const float4*>(&s_h[(320 + k) * TILE]);
      *reinterpret_cast<float4*>(&xr[4]) = *reinterpret_cast<const float4*>(&s_h[(320 + k) * TILE + 4]);
      *reinterpret_cast<float4*>(&xi[0]) = *reinterpret_cast<const float4*>(&s_h[(576 + k) * TILE]);
      *reinterpret_cast<float4*>(&xi[4]) = *reinterpret_cast<const float4*>(&s_h[(576 + k) * TILE + 4]);
#pragma unroll
      for (int e = 0; e < TILE; ++e) {
        ar[e] = fmaf(xr[e], wA, fmaf(-xi[e], wB, ar[e]));
        ai[e] = fmaf(xr[e], wB, fmaf( xi[e], wA, ai[e]));
      }
    }
#pragma unroll
    for (int e = 0; e < TILE; ++e) {
      s_o[(320 + j) * O1P + e] = ar[e];
      s_o[(576 + j) * O1P + e] = ai[e];
    }
  }
  if (t < 192) {
    const int j = t;
    float ar[TILE], ai[TILE];
#pragma unroll
    for (int e = 0; e < TILE; ++e) { ar[e] = 0.f; ai[e] = 0.f; }
#pragma unroll 2
    for (int k = 0; k < 192; ++k) {
      const float wA = n2w[k * 384 + j];
      const float wB = n2w[k * 384 + 192 + j];
      float xr[8], xi[8];
      *reinterpret_cast<float4*>(&xr[0]) = *reinterpret_cast<const float4*>(&s_h[(832 + k) * TILE]);
      *reinterpret_cast<float4*>(&xr[4]) = *reinterpret_cast<const float4*>(&s_h[(832 + k) * TILE + 4]);
      *reinterpret_cast<float4*>(&xi[0]) = *reinterpret_cast<const float4*>(&s_h[(1024 + k) * TILE]);
      *reinterpret_cast<float4*>(&xi[4]) = *reinterpret_cast<const float4*>(&s_h[(1024 + k) * TILE + 4]);
#pragma unroll
      for (int e = 0; e < TILE; ++e) {
        ar[e] = fmaf(xr[e], wA, fmaf(-xi[e], wB, ar[e]));
        ai[e] = fmaf(xr[e], wB, fmaf( xi[e], wA, ai[e]));
      }
    }
#pragma unroll
    for (int e = 0; e < TILE; ++e) {
      s_o[(832 + j) * O1P + e]  = ar[e];
      s_o[(1024 + j) * O1P + e] = ai[e];
    }
  }
  __syncthreads();
  for (int i = t; i < 475 * TILE; i += 256) s_h[i] = winv[(size_t)e0 * 475 + i];
  __syncthreads();
  {
    const int cc = t & 63;
    const int fg = t >> 6;
    for (int e = 0; e < TILE; ++e) {
      const int eg = e0 + e;
      const float dd = edge_dist[eg] * (1.f / 6.f);
      float env = 0.f;
      if (dd < 1.f) {
        const float d5 = dd * dd * dd * dd * dd;
        env = 1.f - 21.f * d5 + 35.f * d5 * dd - 15.f * d5 * dd * dd;
      }
      const int dst = edge_index[NE + eg];
      float* obase = out + (size_t)dst * 1600 + cc;
      const float* wv = &s_h[e * 475];
      for (int f = fg; f < 25; f += 4) {
        float acc = 0.f;
#pragma unroll
        for (int m = 0; m < 19; ++m)
          acc = fmaf(wv[f * 19 + m], s_o[(m * 64 + cc) * O1P + e], acc);
        atomicAdd(obase + f * 64, acc * env);
      }
    }
  }
}

// ==================== host ====================
static inline size_t al256(size_t v) { return (v + 255) & ~(size_t)255; }

extern "C" void kernel_launch(void* const* d_in, const int* in_sizes, int n_in,
                              void* d_out, int out_size, void* d_ws, size_t ws_size,
                              hipStream_t stream) {
  (void)in_sizes; (void)n_in;
  const float* x    = (const float*)d_in[0];
  const float* xe   = (const float*)d_in[1];
  const float* ed   = (const float*)d_in[2];
  const int*   eidx = (const int*)  d_in[3];
  const float* wg   = (const float*)d_in[4];
  const float* wi   = (const float*)d_in[5];
  const float* rw0  = (const float*)d_in[6];
  const float* rb0  = (const float*)d_in[7];
  const float* rg0  = (const float*)d_in[8];
  const float* rbe0 = (const float*)d_in[9];
  const float* rw1  = (const float*)d_in[10];
  const float* rb1  = (const float*)d_in[11];
  const float* rg1  = (const float*)d_in[12];
  const float* rbe1 = (const float*)d_in[13];
  const float* rw2  = (const float*)d_in[14];
  const float* rb2  = (const float*)d_in[15];
  const float* c1w  = (const float*)d_in[16];
  const float* c1b  = (const float*)d_in[17];
  const float* m1w  = (const float*)d_in[18];
  const float* m2w  = (const float*)d_in[19];
  const float* c2w  = (const float*)d_in[20];
  const float* c2b  = (const float*)d_in[21];
  const float* n1w  = (const float*)d_in[22];
  const float* n2w  = (const float*)d_in[23];
  float* out = (float*)d_out;

  hipMemsetAsync(d_out, 0, (size_t)out_size * sizeof(float), stream);

  char* ws = (char*)d_ws;
  u16* pkC1 = (u16*)(ws + 0);        // 640x576
  u16* pkM1 = (u16*)(ws + 737280);   // 1024x512
  u16* pkM2 = (u16*)(ws + 1785856);  // 768x384
  u16* pkC2 = (u16*)(ws + 2375680);  // 320x320
  u16* pkN1 = (u16*)(ws + 2580480);  // 512x512
  u16* pkN2 = (u16*)(ws + 3104768);  // 384x384
  u16* pkR2 = (u16*)(ws + 3399680);  // 64x1536
  const size_t OFF_H1 = 3596288;

  int Ec = 0;
  {
    const int cands[3] = {40000, 20000, 8000};  // all divide 40000; /32 and /4 exact
    for (int i = 0; i < 3 && !Ec; ++i) {
      const size_t c = (size_t)cands[i];
      const size_t need = OFF_H1 + al256(c * 128) + al256(c * 3072) + c * 4864;
      if (ws_size >= need) Ec = cands[i];
    }
  }

  if (Ec == 0) {  // tiny workspace: fall back to the single fused kernel (round-1)
    edgewise_fused<<<NE / TILE, 256, 0, stream>>>(
        x, xe, ed, eidx, wg, wi, rw0, rb0, rg0, rbe0, rw1, rb1, rg1, rbe1, rw2, rb2,
        c1w, c1b, m1w, m2w, c2w, c2b, n1w, n2w, out);
    return;
  }

  const size_t OFF_RAD = OFF_H1 + al256((size_t)Ec * 128);
  const size_t OFF_MSG = OFF_RAD + al256((size_t)Ec * 3072);
  u16* h1   = (u16*)(ws + OFF_H1);
  u16* radb = (u16*)(ws + OFF_RAD);  // rad[Ec][1536]; later h[Ec][1472]
  u16* msgb = (u16*)(ws + OFF_MSG);  // msg[Ec][2432]; later msg3[Ec][1216]

  // pack weights (bf16, MFMA-B-fragment order); complex convs pre-stacked [wA;-wB | wB;wA]
  pack_plain<<<640, 256, 0, stream>>>(c1w, pkC1, 576);
  pack_cplx <<<1024, 256, 0, stream>>>(m1w, pkM1, 512, 512, 256);
  pack_cplx <<<768, 256, 0, stream>>>(m2w, pkM2, 384, 384, 192);
  pack_plain<<<320, 256, 0, stream>>>(c2w, pkC2, 320);
  pack_cplx <<<512, 256, 0, stream>>>(n1w, pkN1, 256, 512, 256);
  pack_cplx <<<384, 256, 0, stream>>>(n2w, pkN2, 192, 384, 192);
  pack_plain<<<64, 256, 0, stream>>>(rw2, pkR2, 1536);

  const int nCh = NE / Ec;
  for (int c = 0; c < nCh; ++c) {
    const int eBase = c * Ec;
    const int MT = (Ec + 127) / 128;
    radial_front<<<Ec / 32, 256, 0, stream>>>(xe, eBase, rw0, rb0, rg0, rbe0,
                                              rw1, rb1, rg1, rbe1, h1);
    gemm_bf16<<<dim3(24, MT), 256, 0, stream>>>(h1, 64, 0, pkR2, rb2, radb, 1536, 0, 1536, 64, Ec);
    wigner_fwd<<<Ec / 4, 256, 0, stream>>>(x, eidx, wg, radb, msgb, eBase);
    // conv1 (writes h into radb; rad is dead after wigner_fwd)
    gemm_bf16<<<dim3(9, MT), 256, 0, stream>>>(msgb, 2432, 0,    pkC1, c1b,    radb, 1472, 0,    576, 640,  Ec);
    gemm_bf16<<<dim3(8, MT), 256, 0, stream>>>(msgb, 2432, 640,  pkM1, nullptr, radb, 1472, 576,  512, 1024, Ec);
    gemm_bf16<<<dim3(6, MT), 256, 0, stream>>>(msgb, 2432, 1664, pkM2, nullptr, radb, 1472, 1088, 384, 768,  Ec);
    gate_kernel<<<Ec / 4, 256, 0, stream>>>(radb, Ec);
    // conv2 (writes msg3 into msgb; msg is dead after conv1)
    gemm_bf16<<<dim3(5, MT), 256, 0, stream>>>(radb, 1472, 0,   pkC2, c2b,    msgb, 1216, 0,   320, 320, Ec);
    gemm_bf16<<<dim3(8, MT), 256, 0, stream>>>(radb, 1472, 320, pkN1, nullptr, msgb, 1216, 320, 512, 512, Ec);
    gemm_bf16<<<dim3(6, MT), 256, 0, stream>>>(radb, 1472, 832, pkN2, nullptr, msgb, 1216, 832, 384, 384, Ec);
    scatter_kernel<<<Ec / 4, 256, 0, stream>>>(msgb, eidx, ed, wi, out, eBase);
  }
}